// Round 4
// baseline (852.888 us; speedup 1.0000x reference)
//
#include <hip/hip_runtime.h>
#include <math.h>

#define Bb 64
#define Tt 512
#define Dd 1536
#define Hh 30
#define NC 128            // packed GX cols: 120 gates + ax + bx + 6 pad (pad values unused)
#define Mm (Bb*Tt)        // 32768 rows
#define KC 32             // gemm k per iteration
#define XSTR 72           // Xs row stride (floats)
#define WSTR 132          // Ws row stride (floats)

__device__ __forceinline__ float sigmoidf_(float x) {
    return 1.f / (1.f + __expf(-x));
}
__device__ __forceinline__ float tanhf_fast(float x) {
    float e = __expf(2.f * x);
    return 1.f - 2.f / (e + 1.f);
}
__device__ __forceinline__ float softplus_(float x) {
    return fmaxf(x, 0.f) + __logf(1.f + __expf(-fabsf(x)));
}
__device__ __forceinline__ float rl_f(float v, int lane) {
    return __uint_as_float(__builtin_amdgcn_readlane(__float_as_uint(v), lane));
}

// ---------------- pack 1: Wp[k][c] fp32 k-major ----------------
__global__ __launch_bounds__(256) void pack_w(const float* __restrict__ Wih,
                                              const float* __restrict__ Wa,
                                              const float* __restrict__ Wb,
                                              float* __restrict__ Wp) {
    int idx = blockIdx.x * 256 + threadIdx.x;      // < 1536*128
    int k = idx >> 7;
    int c = idx & 127;
    float v = 0.f;
    if (c < 120)       v = Wih[c * (Dd + 1) + k];
    else if (c == 120) v = Wa[k];
    else if (c == 121) v = Wb[k];
    Wp[idx] = v;
}

// ---------------- pack 2: scan weight tables WAp/WBp[64][32] ----------------
__global__ __launch_bounds__(256) void pack_s(const float* __restrict__ Wih,
                                              const float* __restrict__ Whh,
                                              const float* __restrict__ Wa,
                                              const float* __restrict__ Wb,
                                              float* __restrict__ WAp,
                                              float* __restrict__ WBp) {
    int t = threadIdx.x;
    for (int idx = t; idx < 64 * 32; idx += 256) {
        int l = idx >> 5, k = idx & 31;
        float va = 0.f, vb = 0.f;
        if (k < 30) {
            if (l < 30)                 { va = Whh[l * Hh + k];        vb = Whh[(30 + l) * Hh + k]; }
            else if (l == 30)           { va = Wa[Dd + k]; }
            else if (l == 31)           { va = Wb[Dd + k]; }
            else if (l < 62)            { va = Whh[(l + 28) * Hh + k]; vb = Whh[(l + 58) * Hh + k]; }
        } else if (k == 30) {
            if (l < 30)                 { va = Wih[l * (Dd + 1) + Dd];        vb = Wih[(30 + l) * (Dd + 1) + Dd]; }
            else if (l >= 32 && l < 62) { va = Wih[(l + 28) * (Dd + 1) + Dd]; vb = Wih[(l + 58) * (Dd + 1) + Dd]; }
        }
        WAp[idx] = va;
        WBp[idx] = vb;
    }
}

// ---------------- gemm: GX[m][c] = X[m,:] @ Wp[:,c] + bias[c], fp32 VALU ----------------
// UNCHANGED from round 3 — will be diagnosed via counters next round.
__global__ __launch_bounds__(256, 2) void gemm_k(const float* __restrict__ X,
                                                 const float* __restrict__ Wp,
                                                 const float* __restrict__ bih,
                                                 const float* __restrict__ bhh,
                                                 const float* __restrict__ ba,
                                                 const float* __restrict__ bbp,
                                                 float* __restrict__ GX) {
    __shared__ float Xs[KC][XSTR];   // transposed: Xs[k][row], rows 0..63
    __shared__ float Ws[KC][WSTR];   // Ws[k][col], cols 0..127
    const int t  = threadIdx.x;
    const int m0 = blockIdx.x * 64;
    const int tc = t & 15;           // col group 0..15
    const int tr = t >> 4;           // row group 0..15
    const int c0 = tc * 8;
    const int r0 = tr * 4;

    float acc[4][8];
#pragma unroll
    for (int r = 0; r < 4; r++)
#pragma unroll
        for (int c = 0; c < 8; c++) acc[r][c] = 0.f;

    const int xr = t >> 3;           // 0..31 (staging row; also handles xr+32)
    const int kk = (t & 7) * 4;      // 0,4,...,28
    const int kw = t >> 3;           // W staging k row 0..31
    const int cw = (t & 7) * 16;     // W staging col base

    for (int k0 = 0; k0 < Dd; k0 += KC) {
        {
            const float4 xv0 = *(const float4*)(X + (size_t)(m0 + xr) * Dd + k0 + kk);
            const float4 xv1 = *(const float4*)(X + (size_t)(m0 + xr + 32) * Dd + k0 + kk);
            Xs[kk + 0][xr] = xv0.x;  Xs[kk + 1][xr] = xv0.y;
            Xs[kk + 2][xr] = xv0.z;  Xs[kk + 3][xr] = xv0.w;
            Xs[kk + 0][xr + 32] = xv1.x;  Xs[kk + 1][xr + 32] = xv1.y;
            Xs[kk + 2][xr + 32] = xv1.z;  Xs[kk + 3][xr + 32] = xv1.w;
        }
        {
            const float* src = Wp + (size_t)(k0 + kw) * NC + cw;
#pragma unroll
            for (int i = 0; i < 4; i++) {
                *(float4*)&Ws[kw][cw + 4 * i] = *(const float4*)(src + 4 * i);
            }
        }
        __syncthreads();
#pragma unroll 8
        for (int k = 0; k < KC; k++) {
            float4 xf  = *(const float4*)&Xs[k][r0];
            float4 wf0 = *(const float4*)&Ws[k][c0];
            float4 wf1 = *(const float4*)&Ws[k][c0 + 4];
            float xr4[4] = {xf.x, xf.y, xf.z, xf.w};
            float wc[8]  = {wf0.x, wf0.y, wf0.z, wf0.w, wf1.x, wf1.y, wf1.z, wf1.w};
#pragma unroll
            for (int r = 0; r < 4; r++)
#pragma unroll
                for (int c = 0; c < 8; c++)
                    acc[r][c] = fmaf(xr4[r], wc[c], acc[r][c]);
        }
        __syncthreads();
    }

    float biasv[8];
#pragma unroll
    for (int c = 0; c < 8; c++) {
        int cc = c0 + c;
        biasv[c] = (cc < 120) ? (bih[cc] + bhh[cc])
                 : (cc == 120) ? ba[0]
                 : (cc == 121) ? bbp[0] : 0.f;
    }
#pragma unroll
    for (int r = 0; r < 4; r++) {
        float4 o0, o1;
        o0.x = acc[r][0] + biasv[0]; o0.y = acc[r][1] + biasv[1];
        o0.z = acc[r][2] + biasv[2]; o0.w = acc[r][3] + biasv[3];
        o1.x = acc[r][4] + biasv[4]; o1.y = acc[r][5] + biasv[5];
        o1.z = acc[r][6] + biasv[6]; o1.w = acc[r][7] + biasv[7];
        float* dst = GX + (size_t)(m0 + r0 + r) * NC + c0;
        *(float4*)(dst + 0) = o0;
        *(float4*)(dst + 4) = o1;
    }
}

// ---------------- scan: one wave per batch row ----------------
// KEY FIX: __launch_bounds__(64, 1) lifts the default 8-waves/SIMD VGPR cap
// (64/wave) that forced the weight tables into scratch remat (VGPR_Count=44,
// ~1700 stall cyc/step in R1/R3). asm pin prevents any residual remat.
__global__ __launch_bounds__(64, 1) void scan_k(const float* __restrict__ u,
                                                const float* __restrict__ gx,
                                                const float* __restrict__ WAp,
                                                const float* __restrict__ WBp,
                                                float* __restrict__ out) {
    __shared__ float lus[Tt];
    __shared__ float zbuf[Tt];
    const int b = blockIdx.x;
    const int l = threadIdx.x;

    for (int k = l; k < Tt; k += 64) {
        float uu = u[b * Tt + k];
        uu = fminf(fmaxf(uu, 1e-5f), 1.f - 1e-5f);
        lus[k] = __logf(1.f - uu);
    }
    __syncthreads();

    // per-lane weights: 32 floats each -> VGPRs, pinned
    float wA[32], wB[32];
#pragma unroll
    for (int j = 0; j < 8; j++) {
        float4 a4 = ((const float4*)(WAp + l * 32))[j];
        float4 b4 = ((const float4*)(WBp + l * 32))[j];
        wA[4 * j + 0] = a4.x; wA[4 * j + 1] = a4.y; wA[4 * j + 2] = a4.z; wA[4 * j + 3] = a4.w;
        wB[4 * j + 0] = b4.x; wB[4 * j + 1] = b4.y; wB[4 * j + 2] = b4.z; wB[4 * j + 3] = b4.w;
    }
#pragma unroll
    for (int k = 0; k < 32; k++) {
        asm volatile("" : "+v"(wA[k]));
        asm volatile("" : "+v"(wB[k]));
    }

    int cA, cB;
    if (l < 30)       { cA = l;       cB = 30 + l; }
    else if (l == 30) { cA = 120;     cB = 122; }
    else if (l == 31) { cA = 121;     cB = 123; }
    else if (l < 62)  { cA = l + 28;  cB = l + 58; }
    else              { cA = 126;     cB = 127; }
    const float* gxb = gx + (size_t)b * Tt * NC;

    float h[Hh];
#pragma unroll
    for (int k = 0; k < Hh; k++) h[k] = 0.f;
    float cst = 0.f;

    // depth-2 software pipeline on GX rows and lu
    float gA0 = gxb[cA], gB0 = gxb[cB];
    float gA1 = gxb[NC + cA], gB1 = gxb[NC + cB];
    float lu0 = lus[0], lu1 = lus[1];

    const int srcb = ((l & 31) + 32) << 2;   // lanes 0..29 pull from 32..61

    for (int t = 0; t < Tt; t++) {
        // 4-way split h-dot to cut FMA dependency chain
        float a0 = gA0, a1 = 0.f, a2 = 0.f, a3 = 0.f;
        float b0 = gB0, b1 = 0.f, b2 = 0.f, b3 = 0.f;
#pragma unroll
        for (int k = 0; k < 28; k += 4) {
            a0 = fmaf(wA[k], h[k], a0);         a1 = fmaf(wA[k + 1], h[k + 1], a1);
            a2 = fmaf(wA[k + 2], h[k + 2], a2); a3 = fmaf(wA[k + 3], h[k + 3], a3);
            b0 = fmaf(wB[k], h[k], b0);         b1 = fmaf(wB[k + 1], h[k + 1], b1);
            b2 = fmaf(wB[k + 2], h[k + 2], b2); b3 = fmaf(wB[k + 3], h[k + 3], b3);
        }
        a0 = fmaf(wA[28], h[28], a0); a1 = fmaf(wA[29], h[29], a1);
        b0 = fmaf(wB[28], h[28], b0); b1 = fmaf(wB[29], h[29], b1);
        float accA = (a0 + a2) + (a1 + a3);
        float accB = (b0 + b2) + (b1 + b3);

        // rotate pipeline, prefetch t+2
        gA0 = gA1; gB0 = gB1;
        float lu = lu0; lu0 = lu1;
        if (t + 2 < Tt) {
            gA1 = gxb[(size_t)(t + 2) * NC + cA];
            gB1 = gxb[(size_t)(t + 2) * NC + cB];
            lu1 = lus[t + 2];
        }

        // a, b scalars from lanes 30/31 (pre z-injection)
        const float av = rl_f(accA, 30);
        const float bv = rl_f(accA, 31);
        float a  = fminf(fmaxf(softplus_(av), 1e-6f), 100.f);
        float bk = fminf(fmaxf(softplus_(bv), 1e-6f), 100.f);
        // HardKuma sample: s = (1 - (1-u)^(1/b))^(1/a)
        float p = __expf(lu / bk);
        float inner = 1.f - p;
        float s = (inner <= 0.f) ? 0.f : __expf(__logf(inner) / a);
        float z = fminf(fmaxf(fmaf(1.2f, s, -0.1f), 0.f), 1.f);

        // inject z * Wih[:,D]
        accA = fmaf(z, wA[30], accA);
        accB = fmaf(z, wB[30], accB);

        // transcendentals BEFORE the permute so they overlap its latency
        const float tg = tanhf_fast(accA);     // tanh(g) valid on upper lanes
        const float sA = sigmoidf_(accA);      // sigmoid(i) valid on lower lanes
        const float sB = sigmoidf_(accB);      // sigmoid(f) lower / sigmoid(o) upper
        const float gg_t = __uint_as_float(__builtin_amdgcn_ds_bpermute(srcb, __float_as_uint(tg)));
        const float oo_s = __uint_as_float(__builtin_amdgcn_ds_bpermute(srcb, __float_as_uint(sB)));

        const float cn = fmaf(sB, cst, sA * gg_t);
        const float hn = oo_s * tanhf_fast(cn);
        cst = cn;
#pragma unroll
        for (int k = 0; k < Hh; k++) h[k] = rl_f(hn, k);
        if (l == 0) zbuf[t] = z;
    }
    __syncthreads();
    for (int k = l; k < Tt; k += 64) out[b * Tt + k] = zbuf[k];
}

extern "C" void kernel_launch(void* const* d_in, const int* in_sizes, int n_in,
                              void* d_out, int out_size, void* d_ws, size_t ws_size,
                              hipStream_t stream) {
    const float* x   = (const float*)d_in[0];
    const float* u   = (const float*)d_in[1];
    const float* Wih = (const float*)d_in[2];
    const float* Whh = (const float*)d_in[3];
    const float* bih = (const float*)d_in[4];
    const float* bhh = (const float*)d_in[5];
    const float* Wa  = (const float*)d_in[6];
    const float* ba  = (const float*)d_in[7];
    const float* Wb  = (const float*)d_in[8];
    const float* bbp = (const float*)d_in[9];
    float* out = (float*)d_out;

    // ws layout (bytes):
    char* wsb = (char*)d_ws;
    float* Wp  = (float*)(wsb);                  // 1536*128*4 = 786432
    float* WAp = (float*)(wsb + 786432);         // 64*32*4 = 8192
    float* WBp = (float*)(wsb + 794624);         // 8192
    float* GX  = (float*)(wsb + 802816);         // 32768*128*4 = 16777216

    pack_w<<<(Dd * NC) / 256, 256, 0, stream>>>(Wih, Wa, Wb, Wp);
    pack_s<<<1, 256, 0, stream>>>(Wih, Whh, Wa, Wb, WAp, WBp);
    gemm_k<<<Mm / 64, 256, 0, stream>>>(x, Wp, bih, bhh, ba, bbp, GX);
    scan_k<<<Bb, 64, 0, stream>>>(u, GX, WAp, WBp, out);
}

// Round 5
// 811.125 us; speedup vs baseline: 1.0515x; 1.0515x over previous
//
#include <hip/hip_runtime.h>
#include <math.h>

#define Bb 64
#define Tt 512
#define Dd 1536
#define Hh 30
#define NC 128            // packed GX cols: 120 gates + ax + bx + 6 pad (pad values unused)
#define Mm (Bb*Tt)        // 32768 rows
#define KC 32             // gemm k per iteration
#define XSTR 72           // Xs row stride (floats)
#define WSTR 132          // Ws row stride (floats)

__device__ __forceinline__ float rcpf_(float x) { return __builtin_amdgcn_rcpf(x); }
__device__ __forceinline__ float sigmoidf_(float x) {
    return rcpf_(1.f + __expf(-x));
}
__device__ __forceinline__ float tanhf_fast(float x) {
    float e = __expf(2.f * x);
    return fmaf(-2.f, rcpf_(e + 1.f), 1.f);
}
__device__ __forceinline__ float softplus_(float x) {
    return fmaxf(x, 0.f) + __logf(1.f + __expf(-fabsf(x)));
}
__device__ __forceinline__ float rl_f(float v, int lane) {
    return __uint_as_float(__builtin_amdgcn_readlane(__float_as_uint(v), lane));
}

// ---------------- pack 1: Wp[k][c] fp32 k-major ----------------
__global__ __launch_bounds__(256) void pack_w(const float* __restrict__ Wih,
                                              const float* __restrict__ Wa,
                                              const float* __restrict__ Wb,
                                              float* __restrict__ Wp) {
    int idx = blockIdx.x * 256 + threadIdx.x;      // < 1536*128
    int k = idx >> 7;
    int c = idx & 127;
    float v = 0.f;
    if (c < 120)       v = Wih[c * (Dd + 1) + k];
    else if (c == 120) v = Wa[k];
    else if (c == 121) v = Wb[k];
    Wp[idx] = v;
}

// ---------------- pack 2: scan weight tables WAp/WBp[64][32] ----------------
__global__ __launch_bounds__(256) void pack_s(const float* __restrict__ Wih,
                                              const float* __restrict__ Whh,
                                              const float* __restrict__ Wa,
                                              const float* __restrict__ Wb,
                                              float* __restrict__ WAp,
                                              float* __restrict__ WBp) {
    int t = threadIdx.x;
    for (int idx = t; idx < 64 * 32; idx += 256) {
        int l = idx >> 5, k = idx & 31;
        float va = 0.f, vb = 0.f;
        if (k < 30) {
            if (l < 30)                 { va = Whh[l * Hh + k];        vb = Whh[(30 + l) * Hh + k]; }
            else if (l == 30)           { va = Wa[Dd + k]; }
            else if (l == 31)           { va = Wb[Dd + k]; }
            else if (l < 62)            { va = Whh[(l + 28) * Hh + k]; vb = Whh[(l + 58) * Hh + k]; }
        } else if (k == 30) {
            if (l < 30)                 { va = Wih[l * (Dd + 1) + Dd];        vb = Wih[(30 + l) * (Dd + 1) + Dd]; }
            else if (l >= 32 && l < 62) { va = Wih[(l + 28) * (Dd + 1) + Dd]; vb = Wih[(l + 58) * (Dd + 1) + Dd]; }
        }
        WAp[idx] = va;
        WBp[idx] = vb;
    }
}

// ---------------- gemm: GX[m][c] = X[m,:] @ Wp[:,c] + bias[c], fp32 VALU ----------------
// UNCHANGED — counters become visible next round once scan_k drops below it.
__global__ __launch_bounds__(256, 2) void gemm_k(const float* __restrict__ X,
                                                 const float* __restrict__ Wp,
                                                 const float* __restrict__ bih,
                                                 const float* __restrict__ bhh,
                                                 const float* __restrict__ ba,
                                                 const float* __restrict__ bbp,
                                                 float* __restrict__ GX) {
    __shared__ float Xs[KC][XSTR];   // transposed: Xs[k][row], rows 0..63
    __shared__ float Ws[KC][WSTR];   // Ws[k][col], cols 0..127
    const int t  = threadIdx.x;
    const int m0 = blockIdx.x * 64;
    const int tc = t & 15;           // col group 0..15
    const int tr = t >> 4;           // row group 0..15
    const int c0 = tc * 8;
    const int r0 = tr * 4;

    float acc[4][8];
#pragma unroll
    for (int r = 0; r < 4; r++)
#pragma unroll
        for (int c = 0; c < 8; c++) acc[r][c] = 0.f;

    const int xr = t >> 3;           // 0..31 (staging row; also handles xr+32)
    const int kk = (t & 7) * 4;      // 0,4,...,28
    const int kw = t >> 3;           // W staging k row 0..31
    const int cw = (t & 7) * 16;     // W staging col base

    for (int k0 = 0; k0 < Dd; k0 += KC) {
        {
            const float4 xv0 = *(const float4*)(X + (size_t)(m0 + xr) * Dd + k0 + kk);
            const float4 xv1 = *(const float4*)(X + (size_t)(m0 + xr + 32) * Dd + k0 + kk);
            Xs[kk + 0][xr] = xv0.x;  Xs[kk + 1][xr] = xv0.y;
            Xs[kk + 2][xr] = xv0.z;  Xs[kk + 3][xr] = xv0.w;
            Xs[kk + 0][xr + 32] = xv1.x;  Xs[kk + 1][xr + 32] = xv1.y;
            Xs[kk + 2][xr + 32] = xv1.z;  Xs[kk + 3][xr + 32] = xv1.w;
        }
        {
            const float* src = Wp + (size_t)(k0 + kw) * NC + cw;
#pragma unroll
            for (int i = 0; i < 4; i++) {
                *(float4*)&Ws[kw][cw + 4 * i] = *(const float4*)(src + 4 * i);
            }
        }
        __syncthreads();
#pragma unroll 8
        for (int k = 0; k < KC; k++) {
            float4 xf  = *(const float4*)&Xs[k][r0];
            float4 wf0 = *(const float4*)&Ws[k][c0];
            float4 wf1 = *(const float4*)&Ws[k][c0 + 4];
            float xr4[4] = {xf.x, xf.y, xf.z, xf.w};
            float wc[8]  = {wf0.x, wf0.y, wf0.z, wf0.w, wf1.x, wf1.y, wf1.z, wf1.w};
#pragma unroll
            for (int r = 0; r < 4; r++)
#pragma unroll
                for (int c = 0; c < 8; c++)
                    acc[r][c] = fmaf(xr4[r], wc[c], acc[r][c]);
        }
        __syncthreads();
    }

    float biasv[8];
#pragma unroll
    for (int c = 0; c < 8; c++) {
        int cc = c0 + c;
        biasv[c] = (cc < 120) ? (bih[cc] + bhh[cc])
                 : (cc == 120) ? ba[0]
                 : (cc == 121) ? bbp[0] : 0.f;
    }
#pragma unroll
    for (int r = 0; r < 4; r++) {
        float4 o0, o1;
        o0.x = acc[r][0] + biasv[0]; o0.y = acc[r][1] + biasv[1];
        o0.z = acc[r][2] + biasv[2]; o0.w = acc[r][3] + biasv[3];
        o1.x = acc[r][4] + biasv[4]; o1.y = acc[r][5] + biasv[5];
        o1.z = acc[r][6] + biasv[6]; o1.w = acc[r][7] + biasv[7];
        float* dst = GX + (size_t)(m0 + r0 + r) * NC + c0;
        *(float4*)(dst + 0) = o0;
        *(float4*)(dst + 4) = o1;
    }
}

// pin 16 array elements into live VGPRs at this program point (zero instructions)
#define PIN16(A, B) asm volatile("" \
    : "+v"(A[B+0]), "+v"(A[B+1]), "+v"(A[B+2]),  "+v"(A[B+3]),  "+v"(A[B+4]),  "+v"(A[B+5]),  "+v"(A[B+6]),  "+v"(A[B+7]), \
      "+v"(A[B+8]), "+v"(A[B+9]), "+v"(A[B+10]), "+v"(A[B+11]), "+v"(A[B+12]), "+v"(A[B+13]), "+v"(A[B+14]), "+v"(A[B+15]))

// ---------------- scan: one wave per batch row ----------------
// IN-LOOP pins: the R4 one-shot pin left VGPR_Count at 44 (allocator re-spilled
// inside the loop). Pinning every iteration makes the weights loop-carried asm
// outputs — reloads are now structurally impossible without 64 loads/iter.
__global__
__attribute__((amdgpu_flat_work_group_size(64, 64)))
__attribute__((amdgpu_waves_per_eu(1)))
void scan_k(const float* __restrict__ u,
            const float* __restrict__ gx,
            const float* __restrict__ WAp,
            const float* __restrict__ WBp,
            float* __restrict__ out) {
    __shared__ float lus[Tt];
    __shared__ float zbuf[Tt];
    const int b = blockIdx.x;
    const int l = threadIdx.x;

    for (int k = l; k < Tt; k += 64) {
        float uu = u[b * Tt + k];
        uu = fminf(fmaxf(uu, 1e-5f), 1.f - 1e-5f);
        lus[k] = __logf(1.f - uu);
    }
    __syncthreads();

    // per-lane weights: 32 floats each -> VGPRs
    float wA[32], wB[32];
#pragma unroll
    for (int j = 0; j < 8; j++) {
        float4 a4 = ((const float4*)(WAp + l * 32))[j];
        float4 b4 = ((const float4*)(WBp + l * 32))[j];
        wA[4 * j + 0] = a4.x; wA[4 * j + 1] = a4.y; wA[4 * j + 2] = a4.z; wA[4 * j + 3] = a4.w;
        wB[4 * j + 0] = b4.x; wB[4 * j + 1] = b4.y; wB[4 * j + 2] = b4.z; wB[4 * j + 3] = b4.w;
    }

    int cA, cB;
    if (l < 30)       { cA = l;       cB = 30 + l; }
    else if (l == 30) { cA = 120;     cB = 122; }
    else if (l == 31) { cA = 121;     cB = 123; }
    else if (l < 62)  { cA = l + 28;  cB = l + 58; }
    else              { cA = 126;     cB = 127; }
    const float* gxb = gx + (size_t)b * Tt * NC;

    float h[Hh];
#pragma unroll
    for (int k = 0; k < Hh; k++) h[k] = 0.f;
    float cst = 0.f;

    // depth-2 software pipeline on GX rows and lu
    float gA0 = gxb[cA], gB0 = gxb[cB];
    float gA1 = gxb[NC + cA], gB1 = gxb[NC + cB];
    float lu0 = lus[0], lu1 = lus[1];

    const int srcb = ((l & 31) + 32) << 2;   // lanes 0..29 pull from 32..61

    for (int t = 0; t < Tt; t++) {
        // force weight residency in VGPRs every iteration (0 instructions)
        PIN16(wA, 0); PIN16(wA, 16);
        PIN16(wB, 0); PIN16(wB, 16);

        // 4-way split h-dot to cut FMA dependency chain
        float a0 = gA0, a1 = 0.f, a2 = 0.f, a3 = 0.f;
        float b0 = gB0, b1 = 0.f, b2 = 0.f, b3 = 0.f;
#pragma unroll
        for (int k = 0; k < 28; k += 4) {
            a0 = fmaf(wA[k], h[k], a0);         a1 = fmaf(wA[k + 1], h[k + 1], a1);
            a2 = fmaf(wA[k + 2], h[k + 2], a2); a3 = fmaf(wA[k + 3], h[k + 3], a3);
            b0 = fmaf(wB[k], h[k], b0);         b1 = fmaf(wB[k + 1], h[k + 1], b1);
            b2 = fmaf(wB[k + 2], h[k + 2], b2); b3 = fmaf(wB[k + 3], h[k + 3], b3);
        }
        a0 = fmaf(wA[28], h[28], a0); a1 = fmaf(wA[29], h[29], a1);
        b0 = fmaf(wB[28], h[28], b0); b1 = fmaf(wB[29], h[29], b1);
        float accA = (a0 + a2) + (a1 + a3);
        float accB = (b0 + b2) + (b1 + b3);

        // rotate pipeline, prefetch t+2
        gA0 = gA1; gB0 = gB1;
        float lu = lu0; lu0 = lu1;
        if (t + 2 < Tt) {
            gA1 = gxb[(size_t)(t + 2) * NC + cA];
            gB1 = gxb[(size_t)(t + 2) * NC + cB];
            lu1 = lus[t + 2];
        }

        // a, b scalars from lanes 30/31 (pre z-injection)
        const float av = rl_f(accA, 30);
        const float bv = rl_f(accA, 31);
        float a  = fminf(fmaxf(softplus_(av), 1e-6f), 100.f);
        float bk = fminf(fmaxf(softplus_(bv), 1e-6f), 100.f);
        // HardKuma sample: s = (1 - (1-u)^(1/b))^(1/a), divides as rcp-muls
        float p = __expf(lu * rcpf_(bk));
        float inner = 1.f - p;
        float s = (inner <= 0.f) ? 0.f : __expf(__logf(inner) * rcpf_(a));
        float z = fminf(fmaxf(fmaf(1.2f, s, -0.1f), 0.f), 1.f);

        // inject z * Wih[:,D]
        accA = fmaf(z, wA[30], accA);
        accB = fmaf(z, wB[30], accB);

        // transcendentals BEFORE the permute so they overlap its latency
        const float tg = tanhf_fast(accA);     // tanh(g) valid on upper lanes
        const float sA = sigmoidf_(accA);      // sigmoid(i) valid on lower lanes
        const float sB = sigmoidf_(accB);      // sigmoid(f) lower / sigmoid(o) upper
        const float gg_t = __uint_as_float(__builtin_amdgcn_ds_bpermute(srcb, __float_as_uint(tg)));
        const float oo_s = __uint_as_float(__builtin_amdgcn_ds_bpermute(srcb, __float_as_uint(sB)));

        const float cn = fmaf(sB, cst, sA * gg_t);
        const float hn = oo_s * tanhf_fast(cn);
        cst = cn;
#pragma unroll
        for (int k = 0; k < Hh; k++) h[k] = rl_f(hn, k);
        if (l == 0) zbuf[t] = z;
    }
    __syncthreads();
    for (int k = l; k < Tt; k += 64) out[b * Tt + k] = zbuf[k];
}

extern "C" void kernel_launch(void* const* d_in, const int* in_sizes, int n_in,
                              void* d_out, int out_size, void* d_ws, size_t ws_size,
                              hipStream_t stream) {
    const float* x   = (const float*)d_in[0];
    const float* u   = (const float*)d_in[1];
    const float* Wih = (const float*)d_in[2];
    const float* Whh = (const float*)d_in[3];
    const float* bih = (const float*)d_in[4];
    const float* bhh = (const float*)d_in[5];
    const float* Wa  = (const float*)d_in[6];
    const float* ba  = (const float*)d_in[7];
    const float* Wb  = (const float*)d_in[8];
    const float* bbp = (const float*)d_in[9];
    float* out = (float*)d_out;

    // ws layout (bytes):
    char* wsb = (char*)d_ws;
    float* Wp  = (float*)(wsb);                  // 1536*128*4 = 786432
    float* WAp = (float*)(wsb + 786432);         // 64*32*4 = 8192
    float* WBp = (float*)(wsb + 794624);         // 8192
    float* GX  = (float*)(wsb + 802816);         // 32768*128*4 = 16777216

    pack_w<<<(Dd * NC) / 256, 256, 0, stream>>>(Wih, Wa, Wb, Wp);
    pack_s<<<1, 256, 0, stream>>>(Wih, Whh, Wa, Wb, WAp, WBp);
    gemm_k<<<Mm / 64, 256, 0, stream>>>(x, Wp, bih, bhh, ba, bbp, GX);
    scan_k<<<Bb, 64, 0, stream>>>(u, GX, WAp, WBp, out);
}